// Round 2
// baseline (464.199 us; speedup 1.0000x reference)
//
#include <hip/hip_runtime.h>

typedef unsigned short u16;
typedef __attribute__((ext_vector_type(8))) short short8;
typedef __attribute__((ext_vector_type(4))) float f32x4;

#define N_NODES 10000
#define N_MOTIFS 2500
#define N_AUG   12500
#define N_EDGES 500000
#define E_TOT   512500   // + self loops
#define NFEAT   512
#define NH1     256      // 2*NHID
#define NH2     128      // NHID

__device__ __forceinline__ float b2f(u16 u){ return __uint_as_float(((unsigned)u) << 16); }
__device__ __forceinline__ u16 f2b(float f){
  unsigned x = __float_as_uint(f);
  x += 0x7fffu + ((x >> 16) & 1u);   // RNE
  return (u16)(x >> 16);
}

// ---------------- small helpers ----------------
__global__ void k_zero(int* p, int n){
  int i = blockIdx.x * blockDim.x + threadIdx.x;
  if (i < n) p[i] = 0;
}

// xaug_bf16 = [x ; mean(x[motif],axis=1)]   (f32 in, bf16 out — GEMM operand)
__global__ void k_xaug(const float* __restrict__ x, const int* __restrict__ motif,
                       u16* __restrict__ xb){
  int gid = blockIdx.x * blockDim.x + threadIdx.x;   // N_AUG * 64 threads, 8 f32 each
  int row = gid >> 6;
  int c   = (gid & 63) << 3;
  if (row >= N_AUG) return;
  float v[8];
  if (row < N_NODES){
    const float* s = &x[(size_t)row * NFEAT + c];
    #pragma unroll
    for (int k = 0; k < 8; ++k) v[k] = s[k];
  } else {
    int m = row - N_NODES;
    const float* p0 = &x[(size_t)motif[m*4+0] * NFEAT + c];
    const float* p1 = &x[(size_t)motif[m*4+1] * NFEAT + c];
    const float* p2 = &x[(size_t)motif[m*4+2] * NFEAT + c];
    const float* p3 = &x[(size_t)motif[m*4+3] * NFEAT + c];
    #pragma unroll
    for (int k = 0; k < 8; ++k) v[k] = (p0[k] + p1[k] + p2[k] + p3[k]) * 0.25f;
  }
  short8 o;
  #pragma unroll
  for (int k = 0; k < 8; ++k) o[k] = (short)f2b(v[k]);
  *(short8*)&xb[(size_t)row * NFEAT + c] = o;
}

// out_bf16[C][R] = in_f32[R][C]
__global__ void k_tr(const float* __restrict__ in, u16* __restrict__ out, int R, int C){
  int i = blockIdx.x * blockDim.x + threadIdx.x;
  if (i >= R * C) return;
  int r = i / C, c = i - r * C;
  out[(size_t)c * R + r] = f2b(in[i]);
}

// out_bf16[i] = in_f32[i]
__global__ void k_cvt(const float* __restrict__ in, u16* __restrict__ out, int n){
  int i = blockIdx.x * blockDim.x + threadIdx.x;
  if (i < n) out[i] = f2b(in[i]);
}

// ---------------- CSR build (sort edges by dst) ----------------
__global__ void k_hist(const int* __restrict__ ei, int* __restrict__ cnt){
  int i = blockIdx.x * blockDim.x + threadIdx.x;
  if (i >= E_TOT) return;
  int d = (i < N_EDGES) ? ei[N_EDGES + i] : (i - N_EDGES);
  atomicAdd(&cnt[d], 1);
}

__global__ void k_scan(const int* __restrict__ cnt, int* __restrict__ offs, int* __restrict__ cur){
  __shared__ int part[1024];
  int t = threadIdx.x;
  const int CH = 13;                    // ceil(12501/1024)
  int base = t * CH;
  int s = 0;
  for (int i = 0; i < CH; ++i){ int idx = base + i; if (idx < N_AUG) s += cnt[idx]; }
  part[t] = s;
  __syncthreads();
  for (int off = 1; off < 1024; off <<= 1){
    int v = 0;
    if (t >= off) v = part[t - off];
    __syncthreads();
    if (t >= off) part[t] += v;
    __syncthreads();
  }
  int run = (t == 0) ? 0 : part[t - 1];
  for (int i = 0; i < CH; ++i){
    int idx = base + i;
    if (idx <= N_AUG){
      offs[idx] = run;
      if (idx < N_AUG){ cur[idx] = run; run += cnt[idx]; }
    }
  }
}

__global__ void k_scatter(const int* __restrict__ ei, int* __restrict__ cur, int* __restrict__ srcs){
  int i = blockIdx.x * blockDim.x + threadIdx.x;
  if (i >= E_TOT) return;
  int s, d;
  if (i < N_EDGES){ s = ei[i]; d = ei[N_EDGES + i]; } else { s = i - N_EDGES; d = s; }
  int pos = atomicAdd(&cur[d], 1);
  srcs[pos] = s;
}

// ---------------- per-node attention coefficients (f32) ----------------
template<int DIM>
__global__ void k_alpha(const float* __restrict__ h, const float* __restrict__ avs,
                        const float* __restrict__ avd, float* __restrict__ oS, float* __restrict__ oD){
  __shared__ float shS[8], shD[8];
  int n = blockIdx.x, t = threadIdx.x;
  int lane = t & 63, wid = t >> 6;
  float hv = h[(size_t)n * DIM + t];
  float s = hv * avs[t];
  float d = hv * avd[t];
  #pragma unroll
  for (int o = 32; o; o >>= 1){ s += __shfl_down(s, o); d += __shfl_down(d, o); }
  if (lane == 0){ shS[wid] = s; shD[wid] = d; }
  __syncthreads();
  if (t == 0){
    float ss = 0.f, dd = 0.f;
    for (int i = 0; i < DIM/64; ++i){ ss += shS[i]; dd += shD[i]; }
    oS[n] = ss; oD[n] = dd;
  }
}

// ---------------- GAT edge-softmax aggregation (one block per dst) ----------------
// h in f32, out written as bf16 (next GEMM operand)
template<int DIM>
__global__ void k_agg(const int* __restrict__ offs, const int* __restrict__ srcs,
                      const float* __restrict__ aS, const float* __restrict__ aD,
                      const float* __restrict__ hb, const float* __restrict__ bias,
                      u16* __restrict__ hout){
  __shared__ float rsh[8];
  __shared__ float wsh[128];
  __shared__ int   ssh[128];
  int d = blockIdx.x, t = threadIdx.x;
  int lane = t & 63, wid = t >> 6;
  const int NW = DIM / 64;
  int r0 = offs[d], r1 = offs[d + 1];
  float adv = aD[d];

  // pass 1: max of leaky_relu(aS[src]+aD[d])
  float mx = -3.0e38f;
  for (int j = r0 + t; j < r1; j += DIM){
    float e = aS[srcs[j]] + adv;
    e = (e >= 0.f) ? e : 0.2f * e;
    mx = fmaxf(mx, e);
  }
  #pragma unroll
  for (int o = 32; o; o >>= 1) mx = fmaxf(mx, __shfl_down(mx, o));
  if (lane == 0) rsh[wid] = mx;
  __syncthreads();
  if (t == 0){ float v = rsh[0]; for (int i = 1; i < NW; ++i) v = fmaxf(v, rsh[i]); rsh[0] = v; }
  __syncthreads();
  mx = rsh[0];
  __syncthreads();

  // pass 2: denom = sum exp(e - mx)
  float sm = 0.f;
  for (int j = r0 + t; j < r1; j += DIM){
    float e = aS[srcs[j]] + adv;
    e = (e >= 0.f) ? e : 0.2f * e;
    sm += __expf(e - mx);
  }
  #pragma unroll
  for (int o = 32; o; o >>= 1) sm += __shfl_down(sm, o);
  if (lane == 0) rsh[wid] = sm;
  __syncthreads();
  if (t == 0){ float v = rsh[0]; for (int i = 1; i < NW; ++i) v += rsh[i]; rsh[0] = v; }
  __syncthreads();
  sm = rsh[0];

  // pass 3: acc[c] = sum_j w_j * h[src_j][c]  (chunked through LDS)
  float acc = 0.f;
  for (int base = r0; base < r1; base += 128){
    int cntE = min(128, r1 - base);
    __syncthreads();
    for (int j = t; j < cntE; j += DIM){
      int s = srcs[base + j];
      ssh[j] = s;
      float e = aS[s] + adv;
      e = (e >= 0.f) ? e : 0.2f * e;
      wsh[j] = __expf(e - mx);
    }
    __syncthreads();
    for (int j = 0; j < cntE; ++j)
      acc += wsh[j] * hb[(size_t)ssh[j] * DIM + t];
  }
  float outv = acc / (sm + 1e-16f) + bias[t];
  hout[(size_t)d * DIM + t] = f2b(outv);
}

// ---------------- NT GEMM: C[M,N] = A[M,K] * B[N,K]^T  (bf16 in, f32 out) ----------------
// EPI: 0 = plain f32 store, 1 = sigmoid, 2 = sigmoid(+bias[col])
template<int EPI>
__global__ __launch_bounds__(256) void k_gemm(
    const u16* __restrict__ A, const u16* __restrict__ B,
    float* __restrict__ C, const float* __restrict__ bias,
    int M, int N, int K){
  __shared__ u16 As[128][72];
  __shared__ u16 Bs[128][72];
  int t = threadIdx.x;
  int lane = t & 63, wid = t >> 6;
  int wm = wid >> 1, wn = wid & 1;
  int m0 = blockIdx.y * 128, n0 = blockIdx.x * 128;

  f32x4 acc[4][4];
  #pragma unroll
  for (int i = 0; i < 4; ++i)
    #pragma unroll
    for (int j = 0; j < 4; ++j)
      acc[i][j] = {0.f, 0.f, 0.f, 0.f};

  for (int k0 = 0; k0 < K; k0 += 64){
    __syncthreads();
    #pragma unroll
    for (int i = 0; i < 4; ++i){
      int id = t + i * 256;
      int r = id >> 3, c = (id & 7) << 3;
      int gm = m0 + r; if (gm >= M) gm = M - 1;
      int gn = n0 + r; if (gn >= N) gn = N - 1;
      *(short8*)&As[r][c] = *(const short8*)&A[(size_t)gm * K + k0 + c];
      *(short8*)&Bs[r][c] = *(const short8*)&B[(size_t)gn * K + k0 + c];
    }
    __syncthreads();
    #pragma unroll
    for (int kk = 0; kk < 2; ++kk){
      int kof = kk * 32 + (lane >> 4) * 8;
      short8 af[4], bfr[4];
      #pragma unroll
      for (int mi = 0; mi < 4; ++mi) af[mi]  = *(const short8*)&As[wm*64 + mi*16 + (lane & 15)][kof];
      #pragma unroll
      for (int ni = 0; ni < 4; ++ni) bfr[ni] = *(const short8*)&Bs[wn*64 + ni*16 + (lane & 15)][kof];
      #pragma unroll
      for (int mi = 0; mi < 4; ++mi)
        #pragma unroll
        for (int ni = 0; ni < 4; ++ni)
          acc[mi][ni] = __builtin_amdgcn_mfma_f32_16x16x32_bf16(af[mi], bfr[ni], acc[mi][ni], 0, 0, 0);
    }
  }

  // C/D layout: col = lane&15, row = (lane>>4)*4 + r   [guide §3, m89]
  #pragma unroll
  for (int mi = 0; mi < 4; ++mi)
    #pragma unroll
    for (int ni = 0; ni < 4; ++ni){
      int gn = n0 + wn*64 + ni*16 + (lane & 15);
      if (gn >= N) continue;
      #pragma unroll
      for (int r = 0; r < 4; ++r){
        int gm = m0 + wm*64 + mi*16 + (lane >> 4)*4 + r;
        if (gm >= M) continue;
        float v = acc[mi][ni][r];
        if (EPI == 2) v += bias[gn];
        if (EPI >= 1) v = 1.f / (1.f + __expf(-v));
        C[(size_t)gm * N + gn] = v;
      }
    }
}

// f32 GEMM output -> also need bf16 copy when it feeds the next GEMM: handled by
// writing agg output directly as bf16 (h1out, h2b). h1pre/h2pre stay f32 for alpha/agg.

// ---------------- launch ----------------
extern "C" void kernel_launch(void* const* d_in, const int* in_sizes, int n_in,
                              void* d_out, int out_size, void* d_ws, size_t ws_size,
                              hipStream_t stream){
  const float* x    = (const float*)d_in[0];
  const int*   ei   = (const int*)d_in[1];
  const int*   mot  = (const int*)d_in[2];
  const float* W1   = (const float*)d_in[3];
  const float* a_s1 = (const float*)d_in[4];
  const float* a_d1 = (const float*)d_in[5];
  const float* b1   = (const float*)d_in[6];
  const float* W2   = (const float*)d_in[7];
  const float* a_s2 = (const float*)d_in[8];
  const float* a_d2 = (const float*)d_in[9];
  const float* b2   = (const float*)d_in[10];
  const float* Wl   = (const float*)d_in[11];
  const float* bl   = (const float*)d_in[12];

  char* p = (char*)d_ws;
  auto alloc = [&](size_t bytes){ void* r = (void*)p; p += (bytes + 255) & ~(size_t)255; return r; };
  u16*   xaugb = (u16*)alloc((size_t)N_AUG * NFEAT * 2);   // bf16 GEMM operand
  u16*   W1T   = (u16*)alloc((size_t)NH1 * NFEAT * 2);
  u16*   W2T   = (u16*)alloc((size_t)NH2 * NH1 * 2);
  u16*   Wlb   = (u16*)alloc((size_t)NFEAT * NH2 * 2);
  float* h1pre = (float*)alloc((size_t)N_AUG * NH1 * 4);   // f32 for alpha/agg
  u16*   h1out = (u16*)alloc((size_t)N_AUG * NH1 * 2);     // bf16 GEMM operand
  float* h2pre = (float*)alloc((size_t)N_AUG * NH2 * 4);
  u16*   h2b   = (u16*)alloc((size_t)N_AUG * NH2 * 2);
  float* aS    = (float*)alloc((size_t)N_AUG * 4);
  float* aD    = (float*)alloc((size_t)N_AUG * 4);
  int*   cnt   = (int*)alloc((size_t)(N_AUG + 8) * 4);
  int*   offs  = (int*)alloc((size_t)(N_AUG + 8) * 4);
  int*   cur   = (int*)alloc((size_t)(N_AUG + 8) * 4);
  int*   srcs  = (int*)alloc((size_t)E_TOT * 4);

  float* out_feat = (float*)d_out;
  float* out_adj  = out_feat + (size_t)N_AUG * NFEAT;

  k_zero<<<(N_AUG + 8 + 255) / 256, 256, 0, stream>>>(cnt, N_AUG + 8);
  k_xaug<<<(N_AUG * 64 + 255) / 256, 256, 0, stream>>>(x, mot, xaugb);
  k_tr<<<(NFEAT * NH1 + 255) / 256, 256, 0, stream>>>(W1, W1T, NFEAT, NH1);
  k_tr<<<(NH1 * NH2 + 255) / 256, 256, 0, stream>>>(W2, W2T, NH1, NH2);
  k_cvt<<<(NFEAT * NH2 + 255) / 256, 256, 0, stream>>>(Wl, Wlb, NFEAT * NH2);
  k_hist<<<(E_TOT + 255) / 256, 256, 0, stream>>>(ei, cnt);
  k_scan<<<1, 1024, 0, stream>>>(cnt, offs, cur);
  k_scatter<<<(E_TOT + 255) / 256, 256, 0, stream>>>(ei, cur, srcs);

  { dim3 g(NH1 / 128, 98); k_gemm<0><<<g, 256, 0, stream>>>(xaugb, W1T, h1pre, nullptr, N_AUG, NH1, NFEAT); }
  k_alpha<NH1><<<N_AUG, NH1, 0, stream>>>(h1pre, a_s1, a_d1, aS, aD);
  k_agg<NH1><<<N_AUG, NH1, 0, stream>>>(offs, srcs, aS, aD, h1pre, b1, h1out);

  { dim3 g(1, 98); k_gemm<0><<<g, 256, 0, stream>>>(h1out, W2T, h2pre, nullptr, N_AUG, NH2, NH1); }
  k_alpha<NH2><<<N_AUG, NH2, 0, stream>>>(h2pre, a_s2, a_d2, aS, aD);
  k_agg<NH2><<<N_AUG, NH2, 0, stream>>>(offs, srcs, aS, aD, h2pre, b2, h2b);

  { dim3 g(NFEAT / 128, 98); k_gemm<2><<<g, 256, 0, stream>>>(h2b, Wlb, out_feat, bl, N_AUG, NFEAT, NH2); }
  { dim3 g(98, 98);          k_gemm<1><<<g, 256, 0, stream>>>(h2b, h2b, out_adj, nullptr, N_AUG, N_AUG, NH2); }
}